// Round 3
// baseline (1385.025 us; speedup 1.0000x reference)
//
#include <hip/hip_runtime.h>
#include <stdint.h>

#define N_CUST 500000
#define N_FUND 50000
#define N_EDGE 4000000
#define D_CUST 101
#define HID 64

struct __align__(16) Accum { float g0, g1, cnt, pad; };

typedef float vf2 __attribute__((ext_vector_type(2)));

__device__ __forceinline__ void atomic_pk_add2(float* p, float x, float y) {
    vf2 v = {x, y};
#if __has_builtin(__builtin_amdgcn_flat_atomic_fadd_v2f32)
    __builtin_amdgcn_flat_atomic_fadd_v2f32((vf2*)p, v);
#elif __has_builtin(__builtin_amdgcn_global_atomic_fadd_v2f32)
    __builtin_amdgcn_global_atomic_fadd_v2f32((vf2*)p, v);
#else
    unsafeAtomicAdd(p, x);
    unsafeAtomicAdd(p + 1, y);
#endif
}

// ---------------------------------------------------------------------------
// k_prep (1 block): Bt = W_r@W_out [128], Af = W_l@W_out [128],
//                   c2 = b_l@W_out + b_out [2]
// ---------------------------------------------------------------------------
__global__ __launch_bounds__(256) void k_prep(
    const float* __restrict__ W_r, const float* __restrict__ W_out,
    const float* __restrict__ b_l, const float* __restrict__ b_out,
    const float* __restrict__ W_l,
    float* __restrict__ Bt, float* __restrict__ Af, float* __restrict__ c2)
{
    int t = threadIdx.x;
    if (t < 128) {
        int h = t >> 1, j = t & 1;
        float s = 0.f, sa = 0.f;
        for (int k = 0; k < 64; ++k) {
            float wo = W_out[k * 2 + j];
            s  = fmaf(W_r[h * 64 + k], wo, s);
            sa = fmaf(W_l[h * 64 + k], wo, sa);
        }
        Bt[t] = s;
        Af[t] = sa;
    } else if (t < 130) {
        int j = t - 128;
        float s = b_out[j];
        for (int k = 0; k < 64; ++k)
            s = fmaf(b_l[k], W_out[k * 2 + j], s);
        c2[j] = s;
    }
}

// ---------------------------------------------------------------------------
// k_gf: gf[f] = relu(x_f[f]*W_fund + b_fund) @ Af     [N_FUND, 2]
// W_fund/b_fund/Af are wave-uniform -> s_loads.
// ---------------------------------------------------------------------------
__global__ __launch_bounds__(256) void k_gf(
    const float* __restrict__ x_fund,
    const float* __restrict__ W_fund,
    const float* __restrict__ b_fund,
    const float* __restrict__ Af,
    float2* __restrict__ gf)
{
    int f = blockIdx.x * 256 + threadIdx.x;
    if (f >= N_FUND) return;
    float xf = x_fund[f];
    float g0 = 0.f, g1 = 0.f;
    #pragma unroll
    for (int h = 0; h < 64; ++h) {
        float hf = fmaxf(fmaf(xf, W_fund[h], b_fund[h]), 0.f);
        g0 = fmaf(hf, Af[2 * h + 0], g0);
        g1 = fmaf(hf, Af[2 * h + 1], g1);
    }
    gf[f] = make_float2(g0, g1);
}

// ---------------------------------------------------------------------------
// k_scatter: 2 atomics/edge. pk_add_f32 (g0,g1) + f32 add (cnt), same 16B.
// ---------------------------------------------------------------------------
__global__ __launch_bounds__(256) void k_scatter(
    const int* __restrict__ src,
    const int* __restrict__ dst,
    const float2* __restrict__ gf,
    Accum* __restrict__ A)
{
    int stride = gridDim.x * 256;
    for (int e = blockIdx.x * 256 + threadIdx.x; e < N_EDGE; e += stride) {
        int s = src[e];
        int d = dst[e];
        float2 g = gf[s];
        atomic_pk_add2(&A[d].g0, g.x, g.y);
        unsafeAtomicAdd(&A[d].cnt, 1.0f);
    }
}

// ---------------------------------------------------------------------------
// k_cust: z = relu(x@W_cust + b_cust); out = mean + z@Bt + c2
// W in SGPRs (uniform s_load), x staged via LDS in 16-wide k-chunks.
// ---------------------------------------------------------------------------
__global__ __launch_bounds__(256, 4) void k_cust(
    const float* __restrict__ x,     // [N_CUST*101]
    const float* __restrict__ Wc,    // [101*64]
    const float* __restrict__ bc,    // [64]
    const float* __restrict__ Bt,    // [128]
    const float* __restrict__ c2,    // [2]
    const Accum* __restrict__ A,     // [N_CUST]
    float2* __restrict__ out)        // [N_CUST]
{
    __shared__ float sX[256 * 17];   // 17-stride pad: conflict-free
    int t = threadIdx.x;
    long base_row = (long)blockIdx.x * 256;

    float a[HID];
    #pragma unroll
    for (int h = 0; h < HID; ++h) a[h] = bc[h];   // uniform s_load

    int kk = t & 15, rg = t >> 4;   // 16 lanes per row-slice, 16 rows/pass

    // 6 full chunks of 16 k, then tail of 5 (96..100)
    #pragma unroll 1
    for (int c = 0; c < 7; ++c) {
        int k0 = c * 16;
        __syncthreads();
        #pragma unroll
        for (int p = 0; p < 16; ++p) {
            int r = p * 16 + rg;
            long row = base_row + r;
            int k = k0 + kk;
            float v = 0.f;
            if (row < N_CUST && k < D_CUST) v = x[row * D_CUST + k];
            sX[r * 17 + kk] = v;
        }
        __syncthreads();
        if (c < 6) {
            #pragma unroll 4
            for (int q = 0; q < 16; ++q) {
                float xk = sX[t * 17 + q];
                int k = k0 + q;
                #pragma unroll
                for (int h = 0; h < HID; ++h)
                    a[h] = fmaf(xk, Wc[k * HID + h], a[h]);   // W uniform -> SGPR
            }
        } else {
            #pragma unroll
            for (int q = 0; q < 5; ++q) {
                float xk = sX[t * 17 + q];
                int k = 96 + q;
                #pragma unroll
                for (int h = 0; h < HID; ++h)
                    a[h] = fmaf(xk, Wc[k * HID + h], a[h]);
            }
        }
    }

    long i = base_row + t;
    if (i < N_CUST) {
        float p0 = c2[0], p1 = c2[1];
        #pragma unroll
        for (int h = 0; h < HID; ++h) {
            float z = fmaxf(a[h], 0.f);
            p0 = fmaf(z, Bt[2 * h + 0], p0);
            p1 = fmaf(z, Bt[2 * h + 1], p1);
        }
        Accum ac = A[i];                        // 16B coalesced
        float inv = 1.0f / fmaxf(ac.cnt, 1.0f);
        out[i] = make_float2(fmaf(ac.g0, inv, p0), fmaf(ac.g1, inv, p1));
    }
}

// ---------------------------------------------------------------------------
extern "C" void kernel_launch(void* const* d_in, const int* in_sizes, int n_in,
                              void* d_out, int out_size, void* d_ws, size_t ws_size,
                              hipStream_t stream) {
    const float* x_customer = (const float*)d_in[0];
    const float* x_fund     = (const float*)d_in[1];
    const int*   src_fund   = (const int*)d_in[2];
    const int*   dst_cust   = (const int*)d_in[3];
    const float* W_cust     = (const float*)d_in[4];
    const float* b_cust     = (const float*)d_in[5];
    const float* W_fund     = (const float*)d_in[6];
    const float* b_fund     = (const float*)d_in[7];
    const float* W_l        = (const float*)d_in[8];
    const float* b_l        = (const float*)d_in[9];
    const float* W_r        = (const float*)d_in[10];
    const float* W_out      = (const float*)d_in[11];
    const float* b_out      = (const float*)d_in[12];

    // workspace layout
    char* ws = (char*)d_ws;
    Accum*  A   = (Accum*)(ws);                     // 8,000,000 B
    float2* gf  = (float2*)(ws + 8000000);          //   400,000 B
    float*  Bt  = (float*)(ws + 8400000);           //       512 B
    float*  Af  = (float*)(ws + 8400512);           //       512 B
    float*  c2  = (float*)(ws + 8401024);           //         8 B

    hipMemsetAsync(A, 0, sizeof(Accum) * (size_t)N_CUST, stream);

    k_prep<<<1, 256, 0, stream>>>(W_r, W_out, b_l, b_out, W_l, Bt, Af, c2);

    k_gf<<<(N_FUND + 255) / 256, 256, 0, stream>>>(x_fund, W_fund, b_fund, Af, gf);

    k_scatter<<<4096, 256, 0, stream>>>(src_fund, dst_cust, gf, A);

    k_cust<<<(N_CUST + 255) / 256, 256, 0, stream>>>(
        x_customer, W_cust, b_cust, Bt, c2, A, (float2*)d_out);
}

// Round 4
// 516.111 us; speedup vs baseline: 2.6836x; 2.6836x over previous
//
#include <hip/hip_runtime.h>
#include <stdint.h>

#define N_CUST 500000
#define N_FUND 50000
#define N_EDGE 4000000
#define D_CUST 101
#define HID 64

#define NB   512                              // partition blocks (S1/S2)
#define EPB  ((N_EDGE + NB - 1) / NB)         // 7813 edges per block
#define CB   1024                             // customers per bucket
#define NBKT ((N_CUST + CB - 1) / CB)         // 489 buckets
#define TILES (N_CUST / 16)                   // 31250 MFMA row-tiles

typedef float  float4u __attribute__((ext_vector_type(4), aligned(4)));
using frag_ab = __attribute__((ext_vector_type(8))) short;   // 8 bf16
using frag_cd = __attribute__((ext_vector_type(4))) float;   // 4 f32

struct __align__(16) Accum { float g0, g1, cnt, pad; };

__device__ __forceinline__ short f2bf(float f) {
    unsigned u = __float_as_uint(f);
    u += 0x7fffu + ((u >> 16) & 1u);          // round-to-nearest-even
    return (short)(u >> 16);
}

// ---------------------------------------------------------------------------
// k_prep: Bt = W_r@W_out [128], Af = W_l@W_out [128], c2 = b_l@W_out + b_out
// ---------------------------------------------------------------------------
__global__ __launch_bounds__(256) void k_prep(
    const float* __restrict__ W_r, const float* __restrict__ W_out,
    const float* __restrict__ b_l, const float* __restrict__ b_out,
    const float* __restrict__ W_l,
    float* __restrict__ Bt, float* __restrict__ Af, float* __restrict__ c2)
{
    int t = threadIdx.x;
    if (t < 128) {
        int h = t >> 1, j = t & 1;
        float s = 0.f, sa = 0.f;
        for (int k = 0; k < 64; ++k) {
            float wo = W_out[k * 2 + j];
            s  = fmaf(W_r[h * 64 + k], wo, s);
            sa = fmaf(W_l[h * 64 + k], wo, sa);
        }
        Bt[t] = s;
        Af[t] = sa;
    } else if (t < 130) {
        int j = t - 128;
        float s = b_out[j];
        for (int k = 0; k < 64; ++k)
            s = fmaf(b_l[k], W_out[k * 2 + j], s);
        c2[j] = s;
    }
}

// ---------------------------------------------------------------------------
// k_gf: gf[f] = relu(x_f[f]*W_fund + b_fund) @ Af
// ---------------------------------------------------------------------------
__global__ __launch_bounds__(256) void k_gf(
    const float* __restrict__ x_fund,
    const float* __restrict__ W_fund,
    const float* __restrict__ b_fund,
    const float* __restrict__ Af,
    float2* __restrict__ gf)
{
    int f = blockIdx.x * 256 + threadIdx.x;
    if (f >= N_FUND) return;
    float xf = x_fund[f];
    float g0 = 0.f, g1 = 0.f;
    #pragma unroll
    for (int h = 0; h < 64; ++h) {
        float hf = fmaxf(fmaf(xf, W_fund[h], b_fund[h]), 0.f);
        g0 = fmaf(hf, Af[2 * h + 0], g0);
        g1 = fmaf(hf, Af[2 * h + 1], g1);
    }
    gf[f] = make_float2(g0, g1);
}

// ---------------------------------------------------------------------------
// S1: per-block LDS histogram of dst buckets -> cntTab[bucket*NB + block]
// ---------------------------------------------------------------------------
__global__ __launch_bounds__(256) void k_count(
    const int* __restrict__ dst, unsigned* __restrict__ cntTab)
{
    __shared__ unsigned hist[NBKT];
    int t = threadIdx.x, b = blockIdx.x;
    for (int k = t; k < NBKT; k += 256) hist[k] = 0;
    __syncthreads();
    int e0 = b * EPB, e1 = min(e0 + EPB, N_EDGE);
    for (int e = e0 + t; e < e1; e += 256)
        atomicAdd(&hist[((unsigned)dst[e]) >> 10], 1u);
    __syncthreads();
    for (int k = t; k < NBKT; k += 256) cntTab[(size_t)k * NB + b] = hist[k];
}

// ---------------------------------------------------------------------------
// Sc1: bucket totals + exclusive scan -> bktBase[0..NBKT]
// ---------------------------------------------------------------------------
__global__ __launch_bounds__(256) void k_scan1(
    const unsigned* __restrict__ cntTab, unsigned* __restrict__ bktBase)
{
    __shared__ unsigned tot[NBKT];
    int t = threadIdx.x;
    for (int k = t; k < NBKT; k += 256) {
        unsigned s = 0;
        const unsigned* row = cntTab + (size_t)k * NB;
        for (int b = 0; b < NB; ++b) s += row[b];
        tot[k] = s;
    }
    __syncthreads();
    if (t < 64) {
        unsigned v[8], pre[8], run = 0;
        #pragma unroll
        for (int j = 0; j < 8; ++j) {
            int idx = t * 8 + j;
            v[j] = (idx < NBKT) ? tot[idx] : 0u;
            pre[j] = run; run += v[j];
        }
        unsigned sc = run;
        #pragma unroll
        for (int d = 1; d < 64; d <<= 1) {
            unsigned n = __shfl_up(sc, d, 64);
            if (t >= d) sc += n;
        }
        unsigned lane_excl = sc - run;
        #pragma unroll
        for (int j = 0; j < 8; ++j) {
            int idx = t * 8 + j;
            if (idx < NBKT) bktBase[idx] = lane_excl + pre[j];
        }
        if (t == 0) bktBase[NBKT] = N_EDGE;
    }
}

// ---------------------------------------------------------------------------
// Sc2: per-bucket exclusive scan over blocks -> offTab[bucket*NB + block]
// ---------------------------------------------------------------------------
__global__ __launch_bounds__(64) void k_scan2(
    const unsigned* __restrict__ cntTab, const unsigned* __restrict__ bktBase,
    unsigned* __restrict__ offTab)
{
    int k = blockIdx.x, l = threadIdx.x;
    const unsigned* row = cntTab + (size_t)k * NB;
    unsigned v[8], pre[8], run = 0;
    #pragma unroll
    for (int j = 0; j < 8; ++j) { v[j] = row[l * 8 + j]; pre[j] = run; run += v[j]; }
    unsigned sc = run;
    #pragma unroll
    for (int d = 1; d < 64; d <<= 1) {
        unsigned n = __shfl_up(sc, d, 64);
        if (l >= d) sc += n;
    }
    unsigned base = bktBase[k] + (sc - run);
    unsigned* orow = offTab + (size_t)k * NB;
    #pragma unroll
    for (int j = 0; j < 8; ++j) orow[l * 8 + j] = base + pre[j];
}

// ---------------------------------------------------------------------------
// S2: reorder edges into bucket-contiguous records via LDS cursors.
// rec = src | (dst_local << 16)   (src < 50000 < 2^16, dst_local < 1024)
// ---------------------------------------------------------------------------
__global__ __launch_bounds__(256) void k_reorder(
    const int* __restrict__ src, const int* __restrict__ dst,
    const unsigned* __restrict__ offTab, unsigned* __restrict__ recs)
{
    __shared__ unsigned cur[NBKT];
    int t = threadIdx.x, b = blockIdx.x;
    for (int k = t; k < NBKT; k += 256) cur[k] = offTab[(size_t)k * NB + b];
    __syncthreads();
    int e0 = b * EPB, e1 = min(e0 + EPB, N_EDGE);
    for (int e = e0 + t; e < e1; e += 256) {
        unsigned d = (unsigned)dst[e];
        unsigned s = (unsigned)src[e];
        unsigned pos = atomicAdd(&cur[d >> 10], 1u);
        recs[pos] = s | ((d & 1023u) << 16);
    }
}

// ---------------------------------------------------------------------------
// S3: one block per bucket: LDS accumulate, write mean directly.
// ---------------------------------------------------------------------------
__global__ __launch_bounds__(256) void k_aggregate(
    const unsigned* __restrict__ recs, const unsigned* __restrict__ bktBase,
    const float2* __restrict__ gf, float2* __restrict__ mean)
{
    __shared__ float s0[CB], s1[CB], scn[CB];
    int t = threadIdx.x, k = blockIdx.x;
    for (int c = t; c < CB; c += 256) { s0[c] = 0.f; s1[c] = 0.f; scn[c] = 0.f; }
    __syncthreads();
    unsigned r0 = bktBase[k], r1 = bktBase[k + 1];
    for (unsigned i = r0 + t; i < r1; i += 256) {
        unsigned r = recs[i];
        float2 g = gf[r & 0xFFFFu];
        unsigned dl = r >> 16;
        atomicAdd(&s0[dl], g.x);
        atomicAdd(&s1[dl], g.y);
        atomicAdd(&scn[dl], 1.f);
    }
    __syncthreads();
    int cust0 = k * CB;
    for (int c = t; c < CB; c += 256) {
        int cu = cust0 + c;
        if (cu < N_CUST) {
            float inv = 1.0f / fmaxf(scn[c], 1.0f);
            mean[cu] = make_float2(s0[c] * inv, s1[c] * inv);
        }
    }
}

// ---------------------------------------------------------------------------
// Fallback scatter (direct global atomics) if ws too small for binning.
// ---------------------------------------------------------------------------
__global__ __launch_bounds__(256) void k_scatter_direct(
    const int* __restrict__ src, const int* __restrict__ dst,
    const float2* __restrict__ gf, Accum* __restrict__ A)
{
    int stride = gridDim.x * 256;
    for (int e = blockIdx.x * 256 + threadIdx.x; e < N_EDGE; e += stride) {
        int s = src[e], d = dst[e];
        float2 g = gf[s];
        unsafeAtomicAdd(&A[d].g0, g.x);
        unsafeAtomicAdd(&A[d].g1, g.y);
        unsafeAtomicAdd(&A[d].cnt, 1.0f);
    }
}

// ---------------------------------------------------------------------------
// k_cust: MFMA GEMM  z = relu(x[500000x101] @ Wc[101x64] + bc)  (bf16 MFMA)
//         out = mean + z @ Bt + c2
// W held entirely in registers as B-fragments; A-frags straight from global.
// ---------------------------------------------------------------------------
template<bool USE_MEAN>
__global__ __launch_bounds__(256) void k_cust(
    const float* __restrict__ x, const float* __restrict__ Wc,
    const float* __restrict__ bc, const float* __restrict__ Bt,
    const float* __restrict__ c2,
    const float2* __restrict__ mean, const Accum* __restrict__ A,
    float2* __restrict__ out)
{
    __shared__ float zb[4][16 * 68];   // wave-private z tiles (17.4 KB)
    int tid = threadIdx.x;
    int w = tid >> 6, lane = tid & 63;
    int c = lane & 15, q = lane >> 4;
    float* z = zb[w];

    // B fragments: bfrag[ntile][kchunk][j] = W[k = kc*32+q*8+j][h = nt*16+c]
    frag_ab bfrag[4][4];
    for (int nt = 0; nt < 4; ++nt)
        for (int kc = 0; kc < 4; ++kc) {
            frag_ab f;
            for (int j = 0; j < 8; ++j) {
                int k = kc * 32 + q * 8 + j;
                int h = nt * 16 + c;
                f[j] = (k < D_CUST) ? f2bf(Wc[k * HID + h]) : (short)0;
            }
            bfrag[nt][kc] = f;
        }
    // Bt slice for this lane's h-range [q*16, q*16+16): 32 contiguous floats
    float btv[32];
    #pragma unroll
    for (int j = 0; j < 8; ++j) {
        float4u v = *(const float4u*)(Bt + q * 32 + j * 4);
        btv[j*4+0] = v[0]; btv[j*4+1] = v[1]; btv[j*4+2] = v[2]; btv[j*4+3] = v[3];
    }
    float bcv[4];
    #pragma unroll
    for (int nt = 0; nt < 4; ++nt) bcv[nt] = bc[nt * 16 + c];
    float c20 = c2[0], c21 = c2[1];

    int wglob = blockIdx.x * 4 + w;
    int wstride = gridDim.x * 4;
    for (int t = wglob; t < TILES; t += wstride) {
        int row = t * 16 + c;                    // A-operand row for this lane
        const float* xr = x + (size_t)row * D_CUST;
        frag_ab af[4];
        #pragma unroll
        for (int kc = 0; kc < 3; ++kc) {
            float4u lo = *(const float4u*)(xr + kc * 32 + q * 8);
            float4u hi = *(const float4u*)(xr + kc * 32 + q * 8 + 4);
            frag_ab f;
            f[0]=f2bf(lo[0]); f[1]=f2bf(lo[1]); f[2]=f2bf(lo[2]); f[3]=f2bf(lo[3]);
            f[4]=f2bf(hi[0]); f[5]=f2bf(hi[1]); f[6]=f2bf(hi[2]); f[7]=f2bf(hi[3]);
            af[kc] = f;
        }
        {   // tail k = 96..127 : only q==0 lanes have valid k (96..100)
            frag_ab f = {0,0,0,0,0,0,0,0};
            if (q == 0) {
                float4u lo = *(const float4u*)(xr + 96);
                f[0]=f2bf(lo[0]); f[1]=f2bf(lo[1]); f[2]=f2bf(lo[2]); f[3]=f2bf(lo[3]);
                f[4]=f2bf(xr[100]);
            }
            af[3] = f;
        }
        frag_cd acc[4];
        #pragma unroll
        for (int nt = 0; nt < 4; ++nt)
            acc[nt] = (frag_cd){bcv[nt], bcv[nt], bcv[nt], bcv[nt]};
        #pragma unroll
        for (int kc = 0; kc < 4; ++kc)
            #pragma unroll
            for (int nt = 0; nt < 4; ++nt)
                acc[nt] = __builtin_amdgcn_mfma_f32_16x16x32_bf16(
                    af[kc], bfrag[nt][kc], acc[nt], 0, 0, 0);

        // relu -> LDS:  C[r = q*4+i][col = nt*16+c]
        #pragma unroll
        for (int nt = 0; nt < 4; ++nt)
            #pragma unroll
            for (int i = 0; i < 4; ++i)
                z[(q * 4 + i) * 68 + nt * 16 + c] = fmaxf(acc[nt][i], 0.f);

        // lane handles z-row r=c, h in [q*16, q*16+16); reduce over q via shfl
        float p0 = 0.f, p1 = 0.f;
        #pragma unroll
        for (int j4 = 0; j4 < 4; ++j4) {
            float4u zv = *(const float4u*)(z + c * 68 + q * 16 + j4 * 4);
            #pragma unroll
            for (int u = 0; u < 4; ++u) {
                int j = j4 * 4 + u;
                p0 = fmaf(zv[u], btv[2 * j + 0], p0);
                p1 = fmaf(zv[u], btv[2 * j + 1], p1);
            }
        }
        p0 += __shfl_xor(p0, 16, 64); p0 += __shfl_xor(p0, 32, 64);
        p1 += __shfl_xor(p1, 16, 64); p1 += __shfl_xor(p1, 32, 64);
        if (q == 0) {
            int orow = t * 16 + c;
            float m0, m1;
            if (USE_MEAN) {
                float2 m = mean[orow]; m0 = m.x; m1 = m.y;
            } else {
                Accum a = A[orow];
                float inv = 1.0f / fmaxf(a.cnt, 1.0f);
                m0 = a.g0 * inv; m1 = a.g1 * inv;
            }
            out[orow] = make_float2(p0 + m0 + c20, p1 + m1 + c21);
        }
    }
}

// ---------------------------------------------------------------------------
extern "C" void kernel_launch(void* const* d_in, const int* in_sizes, int n_in,
                              void* d_out, int out_size, void* d_ws, size_t ws_size,
                              hipStream_t stream) {
    const float* x_customer = (const float*)d_in[0];
    const float* x_fund     = (const float*)d_in[1];
    const int*   src_fund   = (const int*)d_in[2];
    const int*   dst_cust   = (const int*)d_in[3];
    const float* W_cust     = (const float*)d_in[4];
    const float* b_cust     = (const float*)d_in[5];
    const float* W_fund     = (const float*)d_in[6];
    const float* b_fund     = (const float*)d_in[7];
    const float* W_l        = (const float*)d_in[8];
    const float* b_l        = (const float*)d_in[9];
    const float* W_r        = (const float*)d_in[10];
    const float* W_out      = (const float*)d_in[11];
    const float* b_out      = (const float*)d_in[12];

    char* ws = (char*)d_ws;
    const size_t NEED = 22407424;

    if (ws_size >= NEED) {
        // ---- binned path ----
        unsigned* cntTab  = (unsigned*)(ws);                    // 1,001,472
        unsigned* offTab  = (unsigned*)(ws + 1001472);          // 1,001,472
        unsigned* bktBase = (unsigned*)(ws + 2002944);          // 1,960
        float2*   gf      = (float2*)  (ws + 2005248);          // 400,000
        float*    Bt      = (float*)   (ws + 2405248);          // 512
        float*    Af      = (float*)   (ws + 2405760);          // 512
        float*    c2      = (float*)   (ws + 2406272);          // 8
        float2*   mean    = (float2*)  (ws + 2406400);          // 4,000,000
        unsigned* recs    = (unsigned*)(ws + 6406400);          // 16,001,024

        k_prep<<<1, 256, 0, stream>>>(W_r, W_out, b_l, b_out, W_l, Bt, Af, c2);
        k_gf<<<(N_FUND + 255) / 256, 256, 0, stream>>>(x_fund, W_fund, b_fund, Af, gf);
        k_count<<<NB, 256, 0, stream>>>(dst_cust, cntTab);
        k_scan1<<<1, 256, 0, stream>>>(cntTab, bktBase);
        k_scan2<<<NBKT, 64, 0, stream>>>(cntTab, bktBase, offTab);
        k_reorder<<<NB, 256, 0, stream>>>(src_fund, dst_cust, offTab, recs);
        k_aggregate<<<NBKT, 256, 0, stream>>>(recs, bktBase, gf, mean);
        k_cust<true><<<768, 256, 0, stream>>>(
            x_customer, W_cust, b_cust, Bt, c2, mean, nullptr, (float2*)d_out);
    } else {
        // ---- fallback: direct-atomic path (known-good footprint) ----
        Accum*  A  = (Accum*) (ws);                             // 8,000,000
        float2* gf = (float2*)(ws + 8000000);                   // 400,000
        float*  Bt = (float*) (ws + 8400000);
        float*  Af = (float*) (ws + 8400512);
        float*  c2 = (float*) (ws + 8401024);

        hipMemsetAsync(A, 0, sizeof(Accum) * (size_t)N_CUST, stream);
        k_prep<<<1, 256, 0, stream>>>(W_r, W_out, b_l, b_out, W_l, Bt, Af, c2);
        k_gf<<<(N_FUND + 255) / 256, 256, 0, stream>>>(x_fund, W_fund, b_fund, Af, gf);
        k_scatter_direct<<<2048, 256, 0, stream>>>(src_fund, dst_cust, gf, A);
        k_cust<false><<<768, 256, 0, stream>>>(
            x_customer, W_cust, b_cust, Bt, c2, nullptr, A, (float2*)d_out);
    }
}

// Round 5
// 445.287 us; speedup vs baseline: 3.1104x; 1.1591x over previous
//
#include <hip/hip_runtime.h>
#include <stdint.h>

#define N_CUST 500000
#define N_FUND 50000
#define N_EDGE 4000000
#define D_CUST 101
#define HID 64

#define NB   512                              // reorder blocks
#define EPB  ((N_EDGE + NB - 1) / NB)         // 7813 edges per block
#define CB   1024                             // customers per bucket
#define NBKT ((N_CUST + CB - 1) / CB)         // 489 buckets
#define CAP  16384                            // per-bucket record capacity (mean 8180)
#define TILES (N_CUST / 16)                   // 31250 MFMA row-tiles

typedef float  float4u __attribute__((ext_vector_type(4), aligned(4)));
using frag_ab = __attribute__((ext_vector_type(8))) short;   // 8 bf16
using frag_cd = __attribute__((ext_vector_type(4))) float;   // 4 f32

struct __align__(16) Accum { float g0, g1, cnt, pad; };

__device__ __forceinline__ short f2bf(float f) {
    unsigned u = __float_as_uint(f);
    u += 0x7fffu + ((u >> 16) & 1u);          // round-to-nearest-even
    return (short)(u >> 16);
}

// ---------------------------------------------------------------------------
// k_prep: Bt = W_r@W_out, Af = W_l@W_out, c2 = b_l@W_out + b_out,
//         gcur[k] = k*CAP (bucket cursor init)
// ---------------------------------------------------------------------------
__global__ __launch_bounds__(256) void k_prep(
    const float* __restrict__ W_r, const float* __restrict__ W_out,
    const float* __restrict__ b_l, const float* __restrict__ b_out,
    const float* __restrict__ W_l,
    float* __restrict__ Bt, float* __restrict__ Af, float* __restrict__ c2,
    unsigned* __restrict__ gcur)
{
    int t = threadIdx.x;
    if (t < 128) {
        int h = t >> 1, j = t & 1;
        float s = 0.f, sa = 0.f;
        for (int k = 0; k < 64; ++k) {
            float wo = W_out[k * 2 + j];
            s  = fmaf(W_r[h * 64 + k], wo, s);
            sa = fmaf(W_l[h * 64 + k], wo, sa);
        }
        Bt[t] = s;
        Af[t] = sa;
    } else if (t < 130) {
        int j = t - 128;
        float s = b_out[j];
        for (int k = 0; k < 64; ++k)
            s = fmaf(b_l[k], W_out[k * 2 + j], s);
        c2[j] = s;
    }
    for (int k = t; k < NBKT; k += 256) gcur[k] = (unsigned)k * CAP;
}

// ---------------------------------------------------------------------------
// k_gf: gf[f] = relu(x_f[f]*W_fund + b_fund) @ Af
// ---------------------------------------------------------------------------
__global__ __launch_bounds__(256) void k_gf(
    const float* __restrict__ x_fund,
    const float* __restrict__ W_fund,
    const float* __restrict__ b_fund,
    const float* __restrict__ Af,
    float2* __restrict__ gf)
{
    int f = blockIdx.x * 256 + threadIdx.x;
    if (f >= N_FUND) return;
    float xf = x_fund[f];
    float g0 = 0.f, g1 = 0.f;
    #pragma unroll
    for (int h = 0; h < 64; ++h) {
        float hf = fmaxf(fmaf(xf, W_fund[h], b_fund[h]), 0.f);
        g0 = fmaf(hf, Af[2 * h + 0], g0);
        g1 = fmaf(hf, Af[2 * h + 1], g1);
    }
    gf[f] = make_float2(g0, g1);
}

// ---------------------------------------------------------------------------
// k_reorder: single-kernel edge binning.
// Each block LDS-sorts its 7813 edges by bucket (dst>>10), reserves one
// contiguous global chunk per bucket via atomicAdd(gcur), flushes coalesced.
// rec = src | (dst_local << 16).
// ---------------------------------------------------------------------------
__global__ __launch_bounds__(256) void k_reorder(
    const int* __restrict__ src, const int* __restrict__ dst,
    unsigned* __restrict__ gcur, unsigned* __restrict__ recs)
{
    __shared__ unsigned hist[NBKT];
    __shared__ unsigned localOff[NBKT];
    __shared__ unsigned cur[NBKT];
    __shared__ unsigned baseG[NBKT];
    __shared__ unsigned ldsRec[EPB];
    __shared__ unsigned short ldsBkt[EPB];

    int t = threadIdx.x, b = blockIdx.x;
    int e0 = b * EPB, e1 = min(e0 + EPB, N_EDGE);
    int cntE = e1 - e0;

    for (int k = t; k < NBKT; k += 256) hist[k] = 0;
    __syncthreads();
    for (int e = e0 + t; e < e1; e += 256)
        atomicAdd(&hist[((unsigned)dst[e]) >> 10], 1u);
    __syncthreads();

    // one-wave exclusive scan of hist[0..NBKT) -> localOff, cur
    if (t < 64) {
        unsigned v[8], pre[8], run = 0;
        #pragma unroll
        for (int j = 0; j < 8; ++j) {
            int idx = t * 8 + j;
            v[j] = (idx < NBKT) ? hist[idx] : 0u;
            pre[j] = run; run += v[j];
        }
        unsigned sc = run;
        #pragma unroll
        for (int d = 1; d < 64; d <<= 1) {
            unsigned n = __shfl_up(sc, d, 64);
            if (t >= d) sc += n;
        }
        unsigned lane_excl = sc - run;
        #pragma unroll
        for (int j = 0; j < 8; ++j) {
            int idx = t * 8 + j;
            if (idx < NBKT) {
                localOff[idx] = lane_excl + pre[j];
                cur[idx]      = lane_excl + pre[j];
            }
        }
    }
    __syncthreads();

    // reserve global chunks (one atomic per non-empty bucket)
    for (int k = t; k < NBKT; k += 256) {
        unsigned h = hist[k];
        baseG[k] = h ? atomicAdd(&gcur[k], h) : 0u;
    }

    // LDS scatter
    for (int e = e0 + t; e < e1; e += 256) {
        unsigned d = (unsigned)dst[e];
        unsigned s = (unsigned)src[e];
        unsigned k = d >> 10;
        unsigned p = atomicAdd(&cur[k], 1u);
        ldsRec[p] = s | ((d & 1023u) << 16);
        ldsBkt[p] = (unsigned short)k;
    }
    __syncthreads();

    // coalesced flush: consecutive i -> consecutive global within bucket runs
    for (int i = t; i < cntE; i += 256) {
        unsigned k = ldsBkt[i];
        unsigned g = baseG[k] + (i - localOff[k]);
        recs[g] = ldsRec[i];
    }
}

// ---------------------------------------------------------------------------
// k_aggregate: one block per bucket: LDS accumulate, write mean.
// ---------------------------------------------------------------------------
__global__ __launch_bounds__(256) void k_aggregate(
    const unsigned* __restrict__ recs, const unsigned* __restrict__ gcur,
    const float2* __restrict__ gf, float2* __restrict__ mean)
{
    __shared__ float s0[CB], s1[CB], scn[CB];
    int t = threadIdx.x, k = blockIdx.x;
    for (int c = t; c < CB; c += 256) { s0[c] = 0.f; s1[c] = 0.f; scn[c] = 0.f; }
    __syncthreads();
    unsigned r0 = (unsigned)k * CAP, r1 = gcur[k];
    for (unsigned i = r0 + t; i < r1; i += 256) {
        unsigned r = recs[i];
        float2 g = gf[r & 0xFFFFu];
        unsigned dl = r >> 16;
        atomicAdd(&s0[dl], g.x);
        atomicAdd(&s1[dl], g.y);
        atomicAdd(&scn[dl], 1.f);
    }
    __syncthreads();
    int cust0 = k * CB;
    for (int c = t; c < CB; c += 256) {
        int cu = cust0 + c;
        if (cu < N_CUST) {
            float inv = 1.0f / fmaxf(scn[c], 1.0f);
            mean[cu] = make_float2(s0[c] * inv, s1[c] * inv);
        }
    }
}

// ---------------------------------------------------------------------------
// Fallback scatter (direct global atomics) if ws too small.
// ---------------------------------------------------------------------------
__global__ __launch_bounds__(256) void k_scatter_direct(
    const int* __restrict__ src, const int* __restrict__ dst,
    const float2* __restrict__ gf, Accum* __restrict__ A)
{
    int stride = gridDim.x * 256;
    for (int e = blockIdx.x * 256 + threadIdx.x; e < N_EDGE; e += stride) {
        int s = src[e], d = dst[e];
        float2 g = gf[s];
        unsafeAtomicAdd(&A[d].g0, g.x);
        unsafeAtomicAdd(&A[d].g1, g.y);
        unsafeAtomicAdd(&A[d].cnt, 1.0f);
    }
}

// ---------------------------------------------------------------------------
// k_cust: MFMA GEMM  z = relu(x[500000x101] @ Wc[101x64] + bc)  (bf16)
//         out = mean + z @ Bt + c2
// ---------------------------------------------------------------------------
template<bool USE_MEAN>
__global__ __launch_bounds__(256) void k_cust(
    const float* __restrict__ x, const float* __restrict__ Wc,
    const float* __restrict__ bc, const float* __restrict__ Bt,
    const float* __restrict__ c2,
    const float2* __restrict__ mean, const Accum* __restrict__ A,
    float2* __restrict__ out)
{
    __shared__ float zb[4][16 * 68];   // wave-private z tiles (17.4 KB)
    __shared__ float sBt[128];
    int tid = threadIdx.x;
    int w = tid >> 6, lane = tid & 63;
    int c = lane & 15, q = lane >> 4;
    float* z = zb[w];

    if (tid < 128) sBt[tid] = Bt[tid];

    // B fragments: bfrag[ntile][kchunk][j] = W[k = kc*32+q*8+j][h = nt*16+c]
    frag_ab bfrag[4][4];
    for (int nt = 0; nt < 4; ++nt)
        for (int kc = 0; kc < 4; ++kc) {
            frag_ab f;
            for (int j = 0; j < 8; ++j) {
                int k = kc * 32 + q * 8 + j;
                int h = nt * 16 + c;
                f[j] = (k < D_CUST) ? f2bf(Wc[k * HID + h]) : (short)0;
            }
            bfrag[nt][kc] = f;
        }
    float bcv[4];
    #pragma unroll
    for (int nt = 0; nt < 4; ++nt) bcv[nt] = bc[nt * 16 + c];
    float c20 = c2[0], c21 = c2[1];
    __syncthreads();

    int wglob = blockIdx.x * 4 + w;
    int wstride = gridDim.x * 4;
    for (int t = wglob; t < TILES; t += wstride) {
        int row = t * 16 + c;
        const float* xr = x + (size_t)row * D_CUST;
        frag_ab af[4];
        #pragma unroll
        for (int kc = 0; kc < 3; ++kc) {
            float4u lo = *(const float4u*)(xr + kc * 32 + q * 8);
            float4u hi = *(const float4u*)(xr + kc * 32 + q * 8 + 4);
            frag_ab f;
            f[0]=f2bf(lo[0]); f[1]=f2bf(lo[1]); f[2]=f2bf(lo[2]); f[3]=f2bf(lo[3]);
            f[4]=f2bf(hi[0]); f[5]=f2bf(hi[1]); f[6]=f2bf(hi[2]); f[7]=f2bf(hi[3]);
            af[kc] = f;
        }
        {   // tail k = 96..127: only q==0 lanes hold valid k (96..100)
            frag_ab f = {0,0,0,0,0,0,0,0};
            if (q == 0) {
                float4u lo = *(const float4u*)(xr + 96);
                f[0]=f2bf(lo[0]); f[1]=f2bf(lo[1]); f[2]=f2bf(lo[2]); f[3]=f2bf(lo[3]);
                f[4]=f2bf(xr[100]);
            }
            af[3] = f;
        }
        frag_cd acc[4];
        #pragma unroll
        for (int nt = 0; nt < 4; ++nt)
            acc[nt] = (frag_cd){bcv[nt], bcv[nt], bcv[nt], bcv[nt]};
        #pragma unroll
        for (int kc = 0; kc < 4; ++kc)
            #pragma unroll
            for (int nt = 0; nt < 4; ++nt)
                acc[nt] = __builtin_amdgcn_mfma_f32_16x16x32_bf16(
                    af[kc], bfrag[nt][kc], acc[nt], 0, 0, 0);

        // relu -> LDS: C[r = q*4+i][col = nt*16+c]
        #pragma unroll
        for (int nt = 0; nt < 4; ++nt)
            #pragma unroll
            for (int i = 0; i < 4; ++i)
                z[(q * 4 + i) * 68 + nt * 16 + c] = fmaxf(acc[nt][i], 0.f);

        // lane: z-row r=c, h in [q*16, q*16+16); reduce over q via shfl
        float p0 = 0.f, p1 = 0.f;
        #pragma unroll
        for (int j4 = 0; j4 < 4; ++j4) {
            float4u zv = *(const float4u*)(z + c * 68 + q * 16 + j4 * 4);
            float4u b0 = *(const float4u*)(sBt + q * 32 + j4 * 8);      // broadcast
            float4u b1 = *(const float4u*)(sBt + q * 32 + j4 * 8 + 4);
            p0 = fmaf(zv[0], b0[0], p0); p1 = fmaf(zv[0], b0[1], p1);
            p0 = fmaf(zv[1], b0[2], p0); p1 = fmaf(zv[1], b0[3], p1);
            p0 = fmaf(zv[2], b1[0], p0); p1 = fmaf(zv[2], b1[1], p1);
            p0 = fmaf(zv[3], b1[2], p0); p1 = fmaf(zv[3], b1[3], p1);
        }
        p0 += __shfl_xor(p0, 16, 64); p0 += __shfl_xor(p0, 32, 64);
        p1 += __shfl_xor(p1, 16, 64); p1 += __shfl_xor(p1, 32, 64);
        if (q == 0) {
            int orow = t * 16 + c;
            float m0, m1;
            if (USE_MEAN) {
                float2 m = mean[orow]; m0 = m.x; m1 = m.y;
            } else {
                Accum a = A[orow];
                float inv = 1.0f / fmaxf(a.cnt, 1.0f);
                m0 = a.g0 * inv; m1 = a.g1 * inv;
            }
            out[orow] = make_float2(p0 + m0 + c20, p1 + m1 + c21);
        }
    }
}

// ---------------------------------------------------------------------------
extern "C" void kernel_launch(void* const* d_in, const int* in_sizes, int n_in,
                              void* d_out, int out_size, void* d_ws, size_t ws_size,
                              hipStream_t stream) {
    const float* x_customer = (const float*)d_in[0];
    const float* x_fund     = (const float*)d_in[1];
    const int*   src_fund   = (const int*)d_in[2];
    const int*   dst_cust   = (const int*)d_in[3];
    const float* W_cust     = (const float*)d_in[4];
    const float* b_cust     = (const float*)d_in[5];
    const float* W_fund     = (const float*)d_in[6];
    const float* b_fund     = (const float*)d_in[7];
    const float* W_l        = (const float*)d_in[8];
    const float* b_l        = (const float*)d_in[9];
    const float* W_r        = (const float*)d_in[10];
    const float* W_out      = (const float*)d_in[11];
    const float* b_out      = (const float*)d_in[12];

    char* ws = (char*)d_ws;
    const size_t NEED = 4403456ull + (size_t)NBKT * CAP * 4ull + 64;

    if (ws_size >= NEED) {
        float2*   gf   = (float2*)  (ws);                // 400,000
        float*    Bt   = (float*)   (ws + 400000);       // 512
        float*    Af   = (float*)   (ws + 400512);       // 512
        float*    c2   = (float*)   (ws + 401024);       // 8 (+pad)
        unsigned* gcur = (unsigned*)(ws + 401408);       // 1,956 (+pad)
        float2*   mean = (float2*)  (ws + 403456);       // 4,000,000
        unsigned* recs = (unsigned*)(ws + 4403456);      // 32,047,104

        k_prep<<<1, 256, 0, stream>>>(W_r, W_out, b_l, b_out, W_l, Bt, Af, c2, gcur);
        k_gf<<<(N_FUND + 255) / 256, 256, 0, stream>>>(x_fund, W_fund, b_fund, Af, gf);
        k_reorder<<<NB, 256, 0, stream>>>(src_fund, dst_cust, gcur, recs);
        k_aggregate<<<NBKT, 256, 0, stream>>>(recs, gcur, gf, mean);
        k_cust<true><<<1024, 256, 0, stream>>>(
            x_customer, W_cust, b_cust, Bt, c2, mean, nullptr, (float2*)d_out);
    } else {
        // fallback: direct-atomic path
        Accum*    A    = (Accum*) (ws);                  // 8,000,000
        float2*   gf   = (float2*)(ws + 8000000);        // 400,000
        float*    Bt   = (float*) (ws + 8400000);
        float*    Af   = (float*) (ws + 8400512);
        float*    c2   = (float*) (ws + 8401024);
        unsigned* gcur = (unsigned*)(ws + 8401408);

        hipMemsetAsync(A, 0, sizeof(Accum) * (size_t)N_CUST, stream);
        k_prep<<<1, 256, 0, stream>>>(W_r, W_out, b_l, b_out, W_l, Bt, Af, c2, gcur);
        k_gf<<<(N_FUND + 255) / 256, 256, 0, stream>>>(x_fund, W_fund, b_fund, Af, gf);
        k_scatter_direct<<<2048, 256, 0, stream>>>(src_fund, dst_cust, gf, A);
        k_cust<false><<<1024, 256, 0, stream>>>(
            x_customer, W_cust, b_cust, Bt, c2, nullptr, A, (float2*)d_out);
    }
}

// Round 6
// 425.493 us; speedup vs baseline: 3.2551x; 1.0465x over previous
//
#include <hip/hip_runtime.h>
#include <stdint.h>

#define N_CUST 500000
#define N_FUND 50000
#define N_EDGE 4000000
#define D_CUST 101
#define HID 64

#define NB   512                              // reorder blocks
#define EPB  ((N_EDGE + NB - 1) / NB)         // 7813 edges per block
#define CB   512                              // customers per bucket
#define NBKT ((N_CUST + CB - 1) / CB)         // 977 buckets
#define CAP  8192                             // per-bucket capacity (mean 4092, sigma 64)
#define TPB  32                               // tiles per bucket (512/16)

typedef float  float4u __attribute__((ext_vector_type(4), aligned(4)));
using frag_ab = __attribute__((ext_vector_type(8))) short;   // 8 bf16
using frag_cd = __attribute__((ext_vector_type(4))) float;   // 4 f32

struct __align__(16) Accum { float g0, g1, cnt, pad; };

__device__ __forceinline__ short f2bf(float f) {
    unsigned u = __float_as_uint(f);
    u += 0x7fffu + ((u >> 16) & 1u);          // round-to-nearest-even
    return (short)(u >> 16);
}

// ---------------------------------------------------------------------------
// k_gf: gf[f] = relu(x_f[f]*W_fund + b_fund) @ (W_l @ W_out)
// Af computed in-block (reads are L2-hits after block 0).
// ---------------------------------------------------------------------------
__global__ __launch_bounds__(256) void k_gf(
    const float* __restrict__ x_fund,
    const float* __restrict__ W_fund,
    const float* __restrict__ b_fund,
    const float* __restrict__ W_l,
    const float* __restrict__ W_out,
    float2* __restrict__ gf)
{
    __shared__ float sAf[128];
    __shared__ float sWf[64];
    __shared__ float sBf[64];
    int t = threadIdx.x;
    if (t < 128) {
        int h = t >> 1, j = t & 1;
        float s = 0.f;
        for (int k = 0; k < 64; ++k)
            s = fmaf(W_l[h * 64 + k], W_out[k * 2 + j], s);
        sAf[t] = s;
    } else if (t < 192) {
        sWf[t - 128] = W_fund[t - 128];
    } else {
        sBf[t - 192] = b_fund[t - 192];
    }
    __syncthreads();

    int f = blockIdx.x * 256 + t;
    if (f >= N_FUND) return;
    float xf = x_fund[f];
    float g0 = 0.f, g1 = 0.f;
    #pragma unroll
    for (int h = 0; h < 64; ++h) {
        float hf = fmaxf(fmaf(xf, sWf[h], sBf[h]), 0.f);
        g0 = fmaf(hf, sAf[2 * h + 0], g0);
        g1 = fmaf(hf, sAf[2 * h + 1], g1);
    }
    gf[f] = make_float2(g0, g1);
}

// ---------------------------------------------------------------------------
// k_reorder: LDS bucket-sort of each block's 7813 edges, contiguous global
// chunk reservation per bucket, coalesced flush.
// rec = src | (dst_local << 16); bucket = dst >> 9; dl = dst & 511.
// gcur[k] holds running COUNT (zeroed before launch); base = k*CAP + count.
// ---------------------------------------------------------------------------
__global__ __launch_bounds__(256) void k_reorder(
    const int* __restrict__ src, const int* __restrict__ dst,
    unsigned* __restrict__ gcur, unsigned* __restrict__ recs)
{
    __shared__ unsigned hist[NBKT];
    __shared__ unsigned localOff[NBKT];
    __shared__ unsigned cur[NBKT];
    __shared__ unsigned baseG[NBKT];
    __shared__ unsigned ldsRec[EPB];
    __shared__ unsigned short ldsBkt[EPB];

    int t = threadIdx.x, b = blockIdx.x;
    int e0 = b * EPB, e1 = min(e0 + EPB, N_EDGE);
    int cntE = e1 - e0;

    for (int k = t; k < NBKT; k += 256) hist[k] = 0;
    __syncthreads();
    for (int e = e0 + t; e < e1; e += 256)
        atomicAdd(&hist[((unsigned)dst[e]) >> 9], 1u);
    __syncthreads();

    // one-wave exclusive scan of hist[0..NBKT)
    if (t < 64) {
        unsigned v[16], pre[16], run = 0;
        #pragma unroll
        for (int j = 0; j < 16; ++j) {
            int idx = t * 16 + j;
            v[j] = (idx < NBKT) ? hist[idx] : 0u;
            pre[j] = run; run += v[j];
        }
        unsigned sc = run;
        #pragma unroll
        for (int d = 1; d < 64; d <<= 1) {
            unsigned n = __shfl_up(sc, d, 64);
            if (t >= d) sc += n;
        }
        unsigned lane_excl = sc - run;
        #pragma unroll
        for (int j = 0; j < 16; ++j) {
            int idx = t * 16 + j;
            if (idx < NBKT) {
                localOff[idx] = lane_excl + pre[j];
                cur[idx]      = lane_excl + pre[j];
            }
        }
    }
    __syncthreads();

    // reserve global chunks (one atomic per non-empty bucket)
    for (int k = t; k < NBKT; k += 256) {
        unsigned h = hist[k];
        baseG[k] = h ? ((unsigned)k * CAP + atomicAdd(&gcur[k], h)) : 0u;
    }

    // LDS scatter
    for (int e = e0 + t; e < e1; e += 256) {
        unsigned d = (unsigned)dst[e];
        unsigned s = (unsigned)src[e];
        unsigned k = d >> 9;
        unsigned p = atomicAdd(&cur[k], 1u);
        ldsRec[p] = s | ((d & 511u) << 16);
        ldsBkt[p] = (unsigned short)k;
    }
    __syncthreads();

    // coalesced flush
    for (int i = t; i < cntE; i += 256) {
        unsigned k = ldsBkt[i];
        unsigned g = baseG[k] + (i - localOff[k]);
        recs[g] = ldsRec[i];
    }
}

// ---------------------------------------------------------------------------
// k_bucket: per-bucket fused aggregate + MFMA GEMM + epilogue.
// Phase A: accumulate records into LDS (s0,s1,scn).
// Phase B: z = relu(x[512x101] @ Wc + bc); out = mean(LDS) + z@Bt + c2.
// ---------------------------------------------------------------------------
__global__ __launch_bounds__(256) void k_bucket(
    const unsigned* __restrict__ recs, const unsigned* __restrict__ gcur,
    const float2* __restrict__ gf,
    const float* __restrict__ x, const float* __restrict__ Wc,
    const float* __restrict__ bc,
    const float* __restrict__ W_r, const float* __restrict__ W_out,
    const float* __restrict__ b_l, const float* __restrict__ b_out,
    float2* __restrict__ out)
{
    __shared__ float s0[CB], s1[CB], scn[CB];
    __shared__ float sBt[128];
    __shared__ float sc2[2];
    __shared__ float zb[4][16 * 68];

    int t = threadIdx.x, k = blockIdx.x;

    // phase 0: Bt, c2, zero accumulators
    if (t < 128) {
        int h = t >> 1, j = t & 1;
        float s = 0.f;
        for (int kk = 0; kk < 64; ++kk)
            s = fmaf(W_r[h * 64 + kk], W_out[kk * 2 + j], s);
        sBt[t] = s;
    } else if (t < 130) {
        int j = t - 128;
        float s = b_out[j];
        for (int kk = 0; kk < 64; ++kk)
            s = fmaf(b_l[kk], W_out[kk * 2 + j], s);
        sc2[j] = s;
    }
    for (int c = t; c < CB; c += 256) { s0[c] = 0.f; s1[c] = 0.f; scn[c] = 0.f; }
    __syncthreads();

    // phase A: aggregate
    unsigned r0 = (unsigned)k * CAP, r1 = r0 + gcur[k];
    for (unsigned i = r0 + t; i < r1; i += 256) {
        unsigned r = recs[i];
        float2 g = gf[r & 0xFFFFu];
        unsigned dl = r >> 16;
        atomicAdd(&s0[dl], g.x);
        atomicAdd(&s1[dl], g.y);
        atomicAdd(&scn[dl], 1.f);
    }

    // build W fragments while aggregation atomics drain (no sync needed yet)
    int w = t >> 6, lane = t & 63;
    int c = lane & 15, q = lane >> 4;
    float* z = zb[w];
    frag_ab bfrag[4][4];
    for (int nt = 0; nt < 4; ++nt)
        for (int kc = 0; kc < 4; ++kc) {
            frag_ab f;
            for (int j = 0; j < 8; ++j) {
                int kk = kc * 32 + q * 8 + j;
                int h = nt * 16 + c;
                f[j] = (kk < D_CUST) ? f2bf(Wc[kk * HID + h]) : (short)0;
            }
            bfrag[nt][kc] = f;
        }
    float bcv[4];
    #pragma unroll
    for (int nt = 0; nt < 4; ++nt) bcv[nt] = bc[nt * 16 + c];
    __syncthreads();

    float c20 = sc2[0], c21 = sc2[1];
    int cust0 = k * CB;
    int n_tiles = min(TPB, (N_CUST - cust0) >> 4);   // 32, or 18 for last bucket

    // phase B: GEMM, wave w takes tiles w, w+4, ...
    for (int tl = w; tl < n_tiles; tl += 4) {
        int lrow = tl * 16 + c;
        int row = cust0 + lrow;
        const float* xr = x + (size_t)row * D_CUST;
        frag_ab af[4];
        #pragma unroll
        for (int kc = 0; kc < 3; ++kc) {
            float4u lo = *(const float4u*)(xr + kc * 32 + q * 8);
            float4u hi = *(const float4u*)(xr + kc * 32 + q * 8 + 4);
            frag_ab f;
            f[0]=f2bf(lo[0]); f[1]=f2bf(lo[1]); f[2]=f2bf(lo[2]); f[3]=f2bf(lo[3]);
            f[4]=f2bf(hi[0]); f[5]=f2bf(hi[1]); f[6]=f2bf(hi[2]); f[7]=f2bf(hi[3]);
            af[kc] = f;
        }
        {   // tail k = 96..127: only q==0 lanes hold valid k (96..100)
            frag_ab f = {0,0,0,0,0,0,0,0};
            if (q == 0) {
                float4u lo = *(const float4u*)(xr + 96);
                f[0]=f2bf(lo[0]); f[1]=f2bf(lo[1]); f[2]=f2bf(lo[2]); f[3]=f2bf(lo[3]);
                f[4]=f2bf(xr[100]);
            }
            af[3] = f;
        }
        frag_cd acc[4];
        #pragma unroll
        for (int nt = 0; nt < 4; ++nt)
            acc[nt] = (frag_cd){bcv[nt], bcv[nt], bcv[nt], bcv[nt]};
        #pragma unroll
        for (int kc = 0; kc < 4; ++kc)
            #pragma unroll
            for (int nt = 0; nt < 4; ++nt)
                acc[nt] = __builtin_amdgcn_mfma_f32_16x16x32_bf16(
                    af[kc], bfrag[nt][kc], acc[nt], 0, 0, 0);

        // relu -> LDS: C[r = q*4+i][col = nt*16+c]
        #pragma unroll
        for (int nt = 0; nt < 4; ++nt)
            #pragma unroll
            for (int i = 0; i < 4; ++i)
                z[(q * 4 + i) * 68 + nt * 16 + c] = fmaxf(acc[nt][i], 0.f);

        // lane: z-row r=c, h in [q*16, q*16+16); reduce over q via shfl
        float p0 = 0.f, p1 = 0.f;
        #pragma unroll
        for (int j4 = 0; j4 < 4; ++j4) {
            float4u zv = *(const float4u*)(z + c * 68 + q * 16 + j4 * 4);
            float4u b0 = *(const float4u*)(sBt + q * 32 + j4 * 8);
            float4u b1 = *(const float4u*)(sBt + q * 32 + j4 * 8 + 4);
            p0 = fmaf(zv[0], b0[0], p0); p1 = fmaf(zv[0], b0[1], p1);
            p0 = fmaf(zv[1], b0[2], p0); p1 = fmaf(zv[1], b0[3], p1);
            p0 = fmaf(zv[2], b1[0], p0); p1 = fmaf(zv[2], b1[1], p1);
            p0 = fmaf(zv[3], b1[2], p0); p1 = fmaf(zv[3], b1[3], p1);
        }
        p0 += __shfl_xor(p0, 16, 64); p0 += __shfl_xor(p0, 32, 64);
        p1 += __shfl_xor(p1, 16, 64); p1 += __shfl_xor(p1, 32, 64);
        if (q == 0) {
            float inv = 1.0f / fmaxf(scn[lrow], 1.0f);
            out[cust0 + lrow] = make_float2(fmaf(s0[lrow], inv, p0 + c20),
                                            fmaf(s1[lrow], inv, p1 + c21));
        }
    }
}

// ---------------------------------------------------------------------------
// Fallback path kernels (direct atomics) if ws too small.
// ---------------------------------------------------------------------------
__global__ __launch_bounds__(256) void k_prep_fb(
    const float* __restrict__ W_r, const float* __restrict__ W_out,
    const float* __restrict__ b_l, const float* __restrict__ b_out,
    float* __restrict__ Bt, float* __restrict__ c2)
{
    int t = threadIdx.x;
    if (t < 128) {
        int h = t >> 1, j = t & 1;
        float s = 0.f;
        for (int k = 0; k < 64; ++k)
            s = fmaf(W_r[h * 64 + k], W_out[k * 2 + j], s);
        Bt[t] = s;
    } else if (t < 130) {
        int j = t - 128;
        float s = b_out[j];
        for (int k = 0; k < 64; ++k)
            s = fmaf(b_l[k], W_out[k * 2 + j], s);
        c2[j] = s;
    }
}

__global__ __launch_bounds__(256) void k_scatter_direct(
    const int* __restrict__ src, const int* __restrict__ dst,
    const float2* __restrict__ gf, Accum* __restrict__ A)
{
    int stride = gridDim.x * 256;
    for (int e = blockIdx.x * 256 + threadIdx.x; e < N_EDGE; e += stride) {
        int s = src[e], d = dst[e];
        float2 g = gf[s];
        unsafeAtomicAdd(&A[d].g0, g.x);
        unsafeAtomicAdd(&A[d].g1, g.y);
        unsafeAtomicAdd(&A[d].cnt, 1.0f);
    }
}

__global__ __launch_bounds__(256) void k_cust_fb(
    const float* __restrict__ x, const float* __restrict__ Wc,
    const float* __restrict__ bc, const float* __restrict__ Bt,
    const float* __restrict__ c2, const Accum* __restrict__ A,
    float2* __restrict__ out)
{
    __shared__ float zb[4][16 * 68];
    __shared__ float sBt[128];
    int tid = threadIdx.x;
    int w = tid >> 6, lane = tid & 63;
    int c = lane & 15, q = lane >> 4;
    float* z = zb[w];
    if (tid < 128) sBt[tid] = Bt[tid];

    frag_ab bfrag[4][4];
    for (int nt = 0; nt < 4; ++nt)
        for (int kc = 0; kc < 4; ++kc) {
            frag_ab f;
            for (int j = 0; j < 8; ++j) {
                int k = kc * 32 + q * 8 + j;
                f[j] = (k < D_CUST) ? f2bf(Wc[k * HID + nt * 16 + c]) : (short)0;
            }
            bfrag[nt][kc] = f;
        }
    float bcv[4];
    #pragma unroll
    for (int nt = 0; nt < 4; ++nt) bcv[nt] = bc[nt * 16 + c];
    float c20 = c2[0], c21 = c2[1];
    __syncthreads();

    int wglob = blockIdx.x * 4 + w;
    int wstride = gridDim.x * 4;
    for (int t = wglob; t < N_CUST / 16; t += wstride) {
        int row = t * 16 + c;
        const float* xr = x + (size_t)row * D_CUST;
        frag_ab af[4];
        #pragma unroll
        for (int kc = 0; kc < 3; ++kc) {
            float4u lo = *(const float4u*)(xr + kc * 32 + q * 8);
            float4u hi = *(const float4u*)(xr + kc * 32 + q * 8 + 4);
            frag_ab f;
            f[0]=f2bf(lo[0]); f[1]=f2bf(lo[1]); f[2]=f2bf(lo[2]); f[3]=f2bf(lo[3]);
            f[4]=f2bf(hi[0]); f[5]=f2bf(hi[1]); f[6]=f2bf(hi[2]); f[7]=f2bf(hi[3]);
            af[kc] = f;
        }
        {
            frag_ab f = {0,0,0,0,0,0,0,0};
            if (q == 0) {
                float4u lo = *(const float4u*)(xr + 96);
                f[0]=f2bf(lo[0]); f[1]=f2bf(lo[1]); f[2]=f2bf(lo[2]); f[3]=f2bf(lo[3]);
                f[4]=f2bf(xr[100]);
            }
            af[3] = f;
        }
        frag_cd acc[4];
        #pragma unroll
        for (int nt = 0; nt < 4; ++nt)
            acc[nt] = (frag_cd){bcv[nt], bcv[nt], bcv[nt], bcv[nt]};
        #pragma unroll
        for (int kc = 0; kc < 4; ++kc)
            #pragma unroll
            for (int nt = 0; nt < 4; ++nt)
                acc[nt] = __builtin_amdgcn_mfma_f32_16x16x32_bf16(
                    af[kc], bfrag[nt][kc], acc[nt], 0, 0, 0);
        #pragma unroll
        for (int nt = 0; nt < 4; ++nt)
            #pragma unroll
            for (int i = 0; i < 4; ++i)
                z[(q * 4 + i) * 68 + nt * 16 + c] = fmaxf(acc[nt][i], 0.f);
        float p0 = 0.f, p1 = 0.f;
        #pragma unroll
        for (int j4 = 0; j4 < 4; ++j4) {
            float4u zv = *(const float4u*)(z + c * 68 + q * 16 + j4 * 4);
            float4u b0 = *(const float4u*)(sBt + q * 32 + j4 * 8);
            float4u b1 = *(const float4u*)(sBt + q * 32 + j4 * 8 + 4);
            p0 = fmaf(zv[0], b0[0], p0); p1 = fmaf(zv[0], b0[1], p1);
            p0 = fmaf(zv[1], b0[2], p0); p1 = fmaf(zv[1], b0[3], p1);
            p0 = fmaf(zv[2], b1[0], p0); p1 = fmaf(zv[2], b1[1], p1);
            p0 = fmaf(zv[3], b1[2], p0); p1 = fmaf(zv[3], b1[3], p1);
        }
        p0 += __shfl_xor(p0, 16, 64); p0 += __shfl_xor(p0, 32, 64);
        p1 += __shfl_xor(p1, 16, 64); p1 += __shfl_xor(p1, 32, 64);
        if (q == 0) {
            Accum a = A[t * 16 + c];
            float inv = 1.0f / fmaxf(a.cnt, 1.0f);
            out[t * 16 + c] = make_float2(fmaf(a.g0, inv, p0 + c20),
                                          fmaf(a.g1, inv, p1 + c21));
        }
    }
}

// ---------------------------------------------------------------------------
extern "C" void kernel_launch(void* const* d_in, const int* in_sizes, int n_in,
                              void* d_out, int out_size, void* d_ws, size_t ws_size,
                              hipStream_t stream) {
    const float* x_customer = (const float*)d_in[0];
    const float* x_fund     = (const float*)d_in[1];
    const int*   src_fund   = (const int*)d_in[2];
    const int*   dst_cust   = (const int*)d_in[3];
    const float* W_cust     = (const float*)d_in[4];
    const float* b_cust     = (const float*)d_in[5];
    const float* W_fund     = (const float*)d_in[6];
    const float* b_fund     = (const float*)d_in[7];
    const float* W_l        = (const float*)d_in[8];
    const float* b_l        = (const float*)d_in[9];
    const float* W_r        = (const float*)d_in[10];
    const float* W_out      = (const float*)d_in[11];
    const float* b_out      = (const float*)d_in[12];

    char* ws = (char*)d_ws;
    const size_t NEED = 404096ull + (size_t)NBKT * CAP * 4ull;

    if (ws_size >= NEED) {
        float2*   gf   = (float2*)  (ws);                // 400,000
        unsigned* gcur = (unsigned*)(ws + 400000);       // 3,908 (pad to 404,096)
        unsigned* recs = (unsigned*)(ws + 404096);       // 32,014,336

        hipMemsetAsync(gcur, 0, NBKT * sizeof(unsigned), stream);
        k_gf<<<(N_FUND + 255) / 256, 256, 0, stream>>>(
            x_fund, W_fund, b_fund, W_l, W_out, gf);
        k_reorder<<<NB, 256, 0, stream>>>(src_fund, dst_cust, gcur, recs);
        k_bucket<<<NBKT, 256, 0, stream>>>(
            recs, gcur, gf, x_customer, W_cust, b_cust,
            W_r, W_out, b_l, b_out, (float2*)d_out);
    } else {
        Accum*  A  = (Accum*) (ws);                      // 8,000,000
        float2* gf = (float2*)(ws + 8000000);            // 400,000
        float*  Bt = (float*) (ws + 8400000);            // 512
        float*  c2 = (float*) (ws + 8400512);            // 8

        hipMemsetAsync(A, 0, sizeof(Accum) * (size_t)N_CUST, stream);
        k_prep_fb<<<1, 256, 0, stream>>>(W_r, W_out, b_l, b_out, Bt, c2);
        k_gf<<<(N_FUND + 255) / 256, 256, 0, stream>>>(
            x_fund, W_fund, b_fund, W_l, W_out, gf);
        k_scatter_direct<<<2048, 256, 0, stream>>>(src_fund, dst_cust, gf, A);
        k_cust_fb<<<1024, 256, 0, stream>>>(
            x_customer, W_cust, b_cust, Bt, c2, A, (float2*)d_out);
    }
}